// Round 1
// baseline (732.350 us; speedup 1.0000x reference)
//
#include <hip/hip_runtime.h>
#include <math.h>

#define D 128

// Y[r] = X[rowidx ? rowidx[r] : r] @ W (+bias) (optional relu).
// Block = 128 threads (one per output column). W staged in LDS (64 KB),
// row staged in LDS with barriers so X==Y (in-place) is safe.
__global__ void proj128(const float* __restrict__ X, const float* __restrict__ W,
                        const float* __restrict__ bias, const int* __restrict__ rowidx,
                        float* __restrict__ Y, int M, int do_relu) {
    __shared__ float sW[D * D];   // 64 KB
    __shared__ float srow[D];     // 512 B
    const int t = threadIdx.x;    // 0..127
    for (int i = t; i < D * D; i += D) sW[i] = W[i];
    __syncthreads();
    for (int r = blockIdx.x; r < M; r += gridDim.x) {
        const int src = rowidx ? rowidx[r] : r;
        srow[t] = X[(size_t)src * D + t];
        __syncthreads();
        float acc = bias ? bias[t] : 0.0f;
#pragma unroll
        for (int k = 0; k < D; ++k) acc = fmaf(srow[k], sW[k * D + t], acc);
        if (do_relu) acc = fmaxf(acc, 0.0f);
        Y[(size_t)r * D + t] = acc;
        __syncthreads();   // protect srow before next iteration overwrites it
    }
}

// One wave per edge; lane handles 2 contiguous f32 (float2).
__global__ void edge_kernel(const int* __restrict__ edges,
                            const float* __restrict__ hidden,
                            const float* __restrict__ rela,
                            const float* __restrict__ hs_proj,
                            const float* __restrict__ hr_proj,
                            const float* __restrict__ qr_proj,
                            const float* __restrict__ Wa,
                            float* __restrict__ agg, int E) {
    const int gtid = blockIdx.x * blockDim.x + threadIdx.x;
    const int wave = gtid >> 6;
    const int lane = threadIdx.x & 63;
    const int nwaves = (gridDim.x * blockDim.x) >> 6;
    const int c = lane * 2;
    const float2 wa = *(const float2*)(Wa + c);
    for (int e = wave; e < E; e += nwaves) {
        const int r_idx = edges[e * 6 + 0];
        const int rel   = edges[e * 6 + 2];
        const int sub   = edges[e * 6 + 4];
        const int obj   = edges[e * 6 + 5];
        const float2 hp = *(const float2*)(hs_proj + (size_t)sub * D + c);
        const float2 rp = *(const float2*)(hr_proj + (size_t)rel * D + c);
        const float2 qp = *(const float2*)(qr_proj + (size_t)r_idx * D + c);
        float p0 = fmaxf(hp.x + rp.x + qp.x, 0.0f);
        float p1 = fmaxf(hp.y + rp.y + qp.y, 0.0f);
        float part = fmaf(p0, wa.x, p1 * wa.y);
#pragma unroll
        for (int off = 32; off > 0; off >>= 1) part += __shfl_xor(part, off, 64);
        const float alpha = 1.0f / (1.0f + __expf(-part));
        const float2 h  = *(const float2*)(hidden + (size_t)sub * D + c);
        const float2 hr = *(const float2*)(rela + (size_t)rel * D + c);
        atomicAdd(agg + (size_t)obj * D + c,     (h.x + hr.x) * alpha);
        atomicAdd(agg + (size_t)obj * D + c + 1, (h.y + hr.y) * alpha);
    }
}

extern "C" void kernel_launch(void* const* d_in, const int* in_sizes, int n_in,
                              void* d_out, int out_size, void* d_ws, size_t ws_size,
                              hipStream_t stream) {
    const int*   q_rel  = (const int*)d_in[0];
    const float* hidden = (const float*)d_in[1];
    const int*   edges  = (const int*)d_in[2];
    const float* rela   = (const float*)d_in[3];
    const float* Ws     = (const float*)d_in[4];
    const float* Wr     = (const float*)d_in[5];
    const float* Wqr_w  = (const float*)d_in[6];
    const float* Wqr_b  = (const float*)d_in[7];
    const float* Wa     = (const float*)d_in[8];
    const float* Wh     = (const float*)d_in[9];

    const int B = in_sizes[0];
    const int N = in_sizes[1] / D;
    const int E = in_sizes[2] / 6;
    const int R = in_sizes[3] / D;

    float* hs_proj = (float*)d_ws;                       // N*D
    float* hr_proj = hs_proj + (size_t)N * D;            // R*D
    float* qr_proj = hr_proj + (size_t)R * D;            // B*D
    float* agg     = (float*)d_out;                      // N*D, accumulated in-place

    // Precompute projections
    proj128<<<2048, D, 0, stream>>>(hidden, Ws, nullptr, nullptr, hs_proj, N, 0);
    proj128<<<R, D, 0, stream>>>(rela, Wr, nullptr, nullptr, hr_proj, R, 0);
    proj128<<<B, D, 0, stream>>>(rela, Wqr_w, Wqr_b, q_rel, qr_proj, B, 0);

    // Zero the aggregation buffer (d_out) — harness does not re-zero between replays.
    hipMemsetAsync(d_out, 0, (size_t)out_size * sizeof(float), stream);

    // Edge scatter-gather + attention + segment sum
    edge_kernel<<<2048, 256, 0, stream>>>(edges, hidden, rela, hs_proj, hr_proj,
                                          qr_proj, Wa, agg, E);

    // out = relu(agg @ Wh), in-place on d_out
    proj128<<<2048, D, 0, stream>>>(agg, Wh, nullptr, nullptr, agg, N, 1);
}

// Round 2
// 319.358 us; speedup vs baseline: 2.2932x; 2.2932x over previous
//
#include <hip/hip_runtime.h>
#include <math.h>
#include <stdint.h>

#define D 128

// ---------------- histogram of obj ----------------
__global__ void hist_kernel(const int* __restrict__ edges, int* __restrict__ count, int E) {
    const int i = blockIdx.x * blockDim.x + threadIdx.x;
    const int stride = gridDim.x * blockDim.x;
    for (int e = i; e < E; e += stride)
        atomicAdd(&count[edges[e * 6 + 5]], 1);
}

// ---------------- single-block exclusive scan (wave-shuffle based) ----------------
__global__ void scan_kernel(const int* __restrict__ count, int* __restrict__ start,
                            int* __restrict__ cursor, int M) {
    __shared__ int wsum[16];
    __shared__ int s_carry;
    const int t = threadIdx.x;           // 0..1023
    const int lane = t & 63, w = t >> 6; // 16 waves
    if (t == 0) s_carry = 0;
    __syncthreads();
    for (int base = 0; base < M; base += 1024) {
        const int v = (base + t < M) ? count[base + t] : 0;
        // inclusive wave scan
        int x = v;
        #pragma unroll
        for (int off = 1; off < 64; off <<= 1) {
            int y = __shfl_up(x, off, 64);
            if (lane >= off) x += y;
        }
        if (lane == 63) wsum[w] = x;
        __syncthreads();
        if (w == 0) {  // exclusive scan of the 16 wave sums
            int s = (lane < 16) ? wsum[lane] : 0;
            int xs = s;
            #pragma unroll
            for (int off = 1; off < 16; off <<= 1) {
                int y = __shfl_up(xs, off, 64);
                if (lane >= off) xs += y;
            }
            if (lane < 16) wsum[lane] = xs - s;
        }
        __syncthreads();
        const int excl = x - v + wsum[w] + s_carry;  // absolute exclusive prefix
        if (base + t < M) { start[base + t] = excl; cursor[base + t] = excl; }
        __syncthreads();
        if (t == 1023) s_carry = excl + v;           // absolute inclusive total so far
        __syncthreads();
    }
    if (t == 0) start[M] = s_carry;
}

// ---------------- scatter edges into CSR order ----------------
__global__ void scatter_kernel(const int* __restrict__ edges, int* __restrict__ cursor,
                               int4* __restrict__ sorted, int E) {
    const int i = blockIdx.x * blockDim.x + threadIdx.x;
    const int stride = gridDim.x * blockDim.x;
    for (int e = i; e < E; e += stride) {
        const int r_idx = edges[e * 6 + 0];
        const int rel   = edges[e * 6 + 2];
        const int sub   = edges[e * 6 + 4];
        const int obj   = edges[e * 6 + 5];
        const int pos = atomicAdd(&cursor[obj], 1);
        sorted[pos] = make_int4(sub, rel, r_idx, 0);
    }
}

// ---------------- per-node gather aggregation (one wave per node) ----------------
__global__ void agg_kernel(const int4* __restrict__ sorted, const int* __restrict__ start,
                           const float* __restrict__ hidden, const float* __restrict__ rela,
                           const float* __restrict__ hs_proj, const float* __restrict__ hr_proj,
                           const float* __restrict__ qr_proj, const float* __restrict__ Wa,
                           float* __restrict__ out, int N) {
    const int gtid = blockIdx.x * blockDim.x + threadIdx.x;
    const int wave = gtid >> 6;
    const int lane = threadIdx.x & 63;
    const int nwaves = (gridDim.x * blockDim.x) >> 6;
    const int c = lane * 2;
    const float2 wa = *(const float2*)(Wa + c);
    for (int n = wave; n < N; n += nwaves) {
        const int e0 = start[n], e1 = start[n + 1];
        float2 acc = make_float2(0.f, 0.f);
        for (int e = e0; e < e1; ++e) {
            const int4 rec = sorted[e];
            const int sub = rec.x, rel = rec.y, r_idx = rec.z;
            const float2 hp = *(const float2*)(hs_proj + (size_t)sub * D + c);
            const float2 rp = *(const float2*)(hr_proj + (size_t)rel * D + c);
            const float2 qp = *(const float2*)(qr_proj + (size_t)r_idx * D + c);
            const float p0 = fmaxf(hp.x + rp.x + qp.x, 0.f);
            const float p1 = fmaxf(hp.y + rp.y + qp.y, 0.f);
            float part = fmaf(p0, wa.x, p1 * wa.y);
            #pragma unroll
            for (int off = 32; off > 0; off >>= 1) part += __shfl_xor(part, off, 64);
            const float alpha = 1.f / (1.f + __expf(-part));
            const float2 h  = *(const float2*)(hidden + (size_t)sub * D + c);
            const float2 hr = *(const float2*)(rela + (size_t)rel * D + c);
            acc.x += (h.x + hr.x) * alpha;
            acc.y += (h.y + hr.y) * alpha;
        }
        *(float2*)(out + (size_t)n * D + c) = acc;
    }
}

// ---------------- register-blocked 128x128 projection ----------------
// Y[r] = relu?(X[rowidx ? rowidx[r] : r] @ W + bias). Safe for X == Y.
// Block 256 = 4 waves; 32 rows staged per iter; wave computes 8 rows x (2 cols/lane).
__global__ __launch_bounds__(256, 2)
void proj_v2(const float* __restrict__ X, const float* __restrict__ W,
             const float* __restrict__ bias, const int* __restrict__ rowidx,
             float* __restrict__ Y, int M, int do_relu) {
    __shared__ float sW[D * D];     // 64 KB
    __shared__ float srow[32][D];   // 16 KB
    const int t = threadIdx.x;
    {
        const float4* Wv = (const float4*)W;
        float4* sWv = (float4*)sW;
        for (int i = t; i < D * D / 4; i += 256) sWv[i] = Wv[i];
    }
    const int wave = t >> 6, lane = t & 63;
    const int c = lane * 2;
    float2 b = make_float2(0.f, 0.f);
    if (bias) b = *(const float2*)(bias + c);
    __syncthreads();
    for (int r0 = blockIdx.x * 32; r0 < M; r0 += gridDim.x * 32) {
        // stage rows r0..r0+31: thread t -> row t>>3, 64B chunk (t&7)
        {
            const int row = t >> 3, part = t & 7;
            const int gr = r0 + row;
            if (gr < M) {
                const int src = rowidx ? rowidx[gr] : gr;
                const float4* xp = (const float4*)(X + (size_t)src * D + part * 16);
                float4* sp = (float4*)(&srow[row][part * 16]);
                sp[0] = xp[0]; sp[1] = xp[1]; sp[2] = xp[2]; sp[3] = xp[3];
            }
        }
        __syncthreads();
        float2 acc[8];
        #pragma unroll
        for (int r = 0; r < 8; ++r) acc[r] = b;
        for (int k = 0; k < D; k += 4) {
            float4 s[8];
            #pragma unroll
            for (int r = 0; r < 8; ++r) s[r] = *(const float4*)(&srow[wave * 8 + r][k]);
            #pragma unroll
            for (int kk = 0; kk < 4; ++kk) {
                const float2 w = *(const float2*)(&sW[(k + kk) * D + c]);
                #pragma unroll
                for (int r = 0; r < 8; ++r) {
                    const float sv = ((const float*)&s[r])[kk];
                    acc[r].x = fmaf(sv, w.x, acc[r].x);
                    acc[r].y = fmaf(sv, w.y, acc[r].y);
                }
            }
        }
        __syncthreads();   // all srow reads done before stores/next staging
        #pragma unroll
        for (int r = 0; r < 8; ++r) {
            const int gr = r0 + wave * 8 + r;
            if (gr < M) {
                float2 v = acc[r];
                if (do_relu) { v.x = fmaxf(v.x, 0.f); v.y = fmaxf(v.y, 0.f); }
                *(float2*)(Y + (size_t)gr * D + c) = v;
            }
        }
    }
}

extern "C" void kernel_launch(void* const* d_in, const int* in_sizes, int n_in,
                              void* d_out, int out_size, void* d_ws, size_t ws_size,
                              hipStream_t stream) {
    const int*   q_rel  = (const int*)d_in[0];
    const float* hidden = (const float*)d_in[1];
    const int*   edges  = (const int*)d_in[2];
    const float* rela   = (const float*)d_in[3];
    const float* Ws     = (const float*)d_in[4];
    const float* Wr     = (const float*)d_in[5];
    const float* Wqr_w  = (const float*)d_in[6];
    const float* Wqr_b  = (const float*)d_in[7];
    const float* Wa     = (const float*)d_in[8];
    const float* Wh     = (const float*)d_in[9];

    const int B = in_sizes[0];
    const int N = in_sizes[1] / D;
    const int E = in_sizes[2] / 6;
    const int R = in_sizes[3] / D;

    float* hs_proj = (float*)d_ws;                        // N*D
    float* hr_proj = hs_proj + (size_t)N * D;             // R*D
    float* qr_proj = hr_proj + (size_t)R * D;             // B*D
    int*   count   = (int*)(qr_proj + (size_t)B * D);     // N
    int*   start   = count + N;                           // N+1
    int*   cursor  = start + N + 1;                       // N
    int4*  sorted  = (int4*)(((uintptr_t)(cursor + N) + 15) & ~(uintptr_t)15); // E

    // CSR build
    hipMemsetAsync(count, 0, (size_t)N * sizeof(int), stream);
    hist_kernel<<<1024, 256, 0, stream>>>(edges, count, E);
    scan_kernel<<<1, 1024, 0, stream>>>(count, start, cursor, N);
    scatter_kernel<<<1024, 256, 0, stream>>>(edges, cursor, sorted, E);

    // projections
    proj_v2<<<512, 256, 0, stream>>>(hidden, Ws, nullptr, nullptr, hs_proj, N, 0);
    proj_v2<<<(R + 31) / 32, 256, 0, stream>>>(rela, Wr, nullptr, nullptr, hr_proj, R, 0);
    proj_v2<<<(B + 31) / 32, 256, 0, stream>>>(rela, Wqr_w, Wqr_b, q_rel, qr_proj, B, 0);

    // gather aggregation -> d_out (every row written exactly once)
    agg_kernel<<<2048, 256, 0, stream>>>(sorted, start, hidden, rela,
                                         hs_proj, hr_proj, qr_proj, Wa,
                                         (float*)d_out, N);

    // out = relu(agg @ Wh), in-place
    proj_v2<<<512, 256, 0, stream>>>((float*)d_out, Wh, nullptr, nullptr,
                                     (float*)d_out, N, 1);
}

// Round 3
// 254.949 us; speedup vs baseline: 2.8725x; 1.2526x over previous
//
#include <hip/hip_runtime.h>
#include <math.h>
#include <stdint.h>

#define D 128

__device__ inline unsigned pack_bf16(float a, float b) {
    unsigned ua = __float_as_uint(a), ub = __float_as_uint(b);
    ua = (ua + 0x7fffu + ((ua >> 16) & 1u)) >> 16;   // round-to-nearest-even
    ub = (ub + 0x7fffu + ((ub >> 16) & 1u)) >> 16;
    return ua | (ub << 16);
}
__device__ inline float2 bf2_to_f2(unsigned u) {
    return make_float2(__uint_as_float(u << 16), __uint_as_float(u & 0xffff0000u));
}

// ---------------- histogram of obj ----------------
__global__ void hist_kernel(const int* __restrict__ edges, int* __restrict__ count, int E) {
    const int i = blockIdx.x * blockDim.x + threadIdx.x;
    const int stride = gridDim.x * blockDim.x;
    for (int e = i; e < E; e += stride)
        atomicAdd(&count[edges[e * 6 + 5]], 1);
}

// ---------------- 3-phase exclusive scan ----------------
__global__ void scan_partial(const int* __restrict__ count, int* __restrict__ bsum, int M) {
    __shared__ int wsum[16];
    const int t = threadIdx.x, lane = t & 63, w = t >> 6;
    const int i = blockIdx.x * 1024 + t;
    int v = (i < M) ? count[i] : 0;
    #pragma unroll
    for (int off = 32; off > 0; off >>= 1) v += __shfl_xor(v, off, 64);
    if (lane == 0) wsum[w] = v;
    __syncthreads();
    if (w == 0) {
        int s = (lane < 16) ? wsum[lane] : 0;
        #pragma unroll
        for (int off = 8; off > 0; off >>= 1) s += __shfl_xor(s, off, 16);
        if (lane == 0) bsum[blockIdx.x] = s;
    }
}

__global__ void scan_bsum(int* __restrict__ bsum, int G) {  // 1 block, 64 threads, G<=64
    const int t = threadIdx.x;
    const int v = (t < G) ? bsum[t] : 0;
    int x = v;
    #pragma unroll
    for (int off = 1; off < 64; off <<= 1) {
        int y = __shfl_up(x, off, 64);
        if (t >= off) x += y;
    }
    if (t < G) bsum[t] = x - v;
}

__global__ void scan_final(const int* __restrict__ count, const int* __restrict__ bsum,
                           int* __restrict__ start, int* __restrict__ cursor, int M) {
    __shared__ int wsum[16];
    const int t = threadIdx.x, lane = t & 63, w = t >> 6;
    const int i = blockIdx.x * 1024 + t;
    const int v = (i < M) ? count[i] : 0;
    int x = v;
    #pragma unroll
    for (int off = 1; off < 64; off <<= 1) {
        int y = __shfl_up(x, off, 64);
        if (lane >= off) x += y;
    }
    if (lane == 63) wsum[w] = x;
    __syncthreads();
    if (w == 0) {
        int s = (lane < 16) ? wsum[lane] : 0;
        int xs = s;
        #pragma unroll
        for (int off = 1; off < 16; off <<= 1) {
            int y = __shfl_up(xs, off, 64);
            if (lane >= off) xs += y;
        }
        if (lane < 16) wsum[lane] = xs - s;
    }
    __syncthreads();
    const int excl = x - v + wsum[w] + bsum[blockIdx.x];
    if (i < M) {
        start[i] = excl;
        cursor[i] = excl;
        if (i == M - 1) start[M] = excl + v;
    }
}

// ---------------- scatter edges into CSR order, packed uint32 ----------------
// sub:16 | rel:9 | r_idx:7  (N<=65536, R<=512, B<=128)
__global__ void scatter_kernel(const int* __restrict__ edges, int* __restrict__ cursor,
                               unsigned* __restrict__ sorted, int E) {
    const int i = blockIdx.x * blockDim.x + threadIdx.x;
    const int stride = gridDim.x * blockDim.x;
    for (int e = i; e < E; e += stride) {
        const int r_idx = edges[e * 6 + 0];
        const int rel   = edges[e * 6 + 2];
        const int sub   = edges[e * 6 + 4];
        const int obj   = edges[e * 6 + 5];
        const int pos = atomicAdd(&cursor[obj], 1);
        sorted[pos] = (unsigned)sub | ((unsigned)rel << 16) | ((unsigned)r_idx << 25);
    }
}

// ---------------- per-node gather aggregation (one wave per node, bf16 tables) ----------------
__global__ void agg_v3(const unsigned* __restrict__ sorted, const int* __restrict__ start,
                       const unsigned short* __restrict__ combo,    // [N][256]: hidden | hs_proj
                       const unsigned short* __restrict__ hrcombo,  // [R][256]: rela | hr_proj
                       const unsigned short* __restrict__ qrb,      // [B][128]: qr_proj
                       const float* __restrict__ Wa,
                       float* __restrict__ out, int N) {
    const int gtid = blockIdx.x * blockDim.x + threadIdx.x;
    const int wave = gtid >> 6;
    const int lane = threadIdx.x & 63;
    const int nwaves = (gridDim.x * blockDim.x) >> 6;
    const int c = lane * 2;
    const float2 wa = *(const float2*)(Wa + c);
    for (int n = wave; n < N; n += nwaves) {
        const int e0 = start[n], e1 = start[n + 1];
        float2 acc = make_float2(0.f, 0.f);
        for (int e = e0; e < e1; ++e) {
            const unsigned rec = sorted[e];
            const int sub  = rec & 0xFFFF;
            const int rel  = (rec >> 16) & 0x1FF;
            const int ridx = rec >> 25;
            const float2 hid = bf2_to_f2(*(const unsigned*)(combo + (size_t)sub * 256 + c));
            const float2 hsp = bf2_to_f2(*(const unsigned*)(combo + (size_t)sub * 256 + 128 + c));
            const float2 hre = bf2_to_f2(*(const unsigned*)(hrcombo + (size_t)rel * 256 + c));
            const float2 hrp = bf2_to_f2(*(const unsigned*)(hrcombo + (size_t)rel * 256 + 128 + c));
            const float2 qrp = bf2_to_f2(*(const unsigned*)(qrb + (size_t)ridx * 128 + c));
            const float p0 = fmaxf(hsp.x + hrp.x + qrp.x, 0.f);
            const float p1 = fmaxf(hsp.y + hrp.y + qrp.y, 0.f);
            float part = fmaf(p0, wa.x, p1 * wa.y);
            #pragma unroll
            for (int off = 32; off > 0; off >>= 1) part += __shfl_xor(part, off, 64);
            const float alpha = 1.f / (1.f + __expf(-part));
            acc.x += (hid.x + hre.x) * alpha;
            acc.y += (hid.y + hre.y) * alpha;
        }
        *(float2*)(out + (size_t)n * D + c) = acc;
    }
}

// ---------------- register-blocked 128x128 projection ----------------
// MODE 0: f32 out (+optional relu), in-place safe (X==Y).
// MODE 1: bf16 combo out: [r][0:128]=bf16(input row), [r][128:256]=bf16(proj).
// MODE 2: bf16 proj out only.
template<int MODE>
__global__ __launch_bounds__(256, 2)
void proj_t(const float* __restrict__ X, const float* __restrict__ W,
            const float* __restrict__ bias, const int* __restrict__ rowidx,
            void* __restrict__ Yv, int M, int do_relu) {
    __shared__ float sW[D * D];     // 64 KB
    __shared__ float srow[32][D];   // 16 KB
    const int t = threadIdx.x;
    {
        const float4* Wv = (const float4*)W;
        float4* sWv = (float4*)sW;
        for (int i = t; i < D * D / 4; i += 256) sWv[i] = Wv[i];
    }
    const int wave = t >> 6, lane = t & 63;
    const int c = lane * 2;
    float2 b = make_float2(0.f, 0.f);
    if (bias) b = *(const float2*)(bias + c);
    __syncthreads();
    for (int r0 = blockIdx.x * 32; r0 < M; r0 += gridDim.x * 32) {
        {   // stage rows r0..r0+31: thread t -> row t>>3, 64B chunk (t&7)
            const int row = t >> 3, part = t & 7;
            const int gr = r0 + row;
            if (gr < M) {
                const int src = rowidx ? rowidx[gr] : gr;
                const float4* xp = (const float4*)(X + (size_t)src * D + part * 16);
                float4* sp = (float4*)(&srow[row][part * 16]);
                sp[0] = xp[0]; sp[1] = xp[1]; sp[2] = xp[2]; sp[3] = xp[3];
            }
        }
        __syncthreads();
        float2 acc[8];
        #pragma unroll
        for (int r = 0; r < 8; ++r) acc[r] = b;
        for (int k = 0; k < D; k += 4) {
            float4 s[8];
            #pragma unroll
            for (int r = 0; r < 8; ++r) s[r] = *(const float4*)(&srow[wave * 8 + r][k]);
            #pragma unroll
            for (int kk = 0; kk < 4; ++kk) {
                const float2 w = *(const float2*)(&sW[(k + kk) * D + c]);
                #pragma unroll
                for (int r = 0; r < 8; ++r) {
                    const float sv = (&s[r].x)[kk];
                    acc[r].x = fmaf(sv, w.x, acc[r].x);
                    acc[r].y = fmaf(sv, w.y, acc[r].y);
                }
            }
        }
        // epilogue BEFORE the trailing barrier (MODE 1 reads srow here)
        #pragma unroll
        for (int r = 0; r < 8; ++r) {
            const int gr = r0 + wave * 8 + r;
            if (gr < M) {
                if (MODE == 0) {
                    float2 v = acc[r];
                    if (do_relu) { v.x = fmaxf(v.x, 0.f); v.y = fmaxf(v.y, 0.f); }
                    *(float2*)((float*)Yv + (size_t)gr * D + c) = v;
                } else if (MODE == 1) {
                    unsigned short* Yb = (unsigned short*)Yv;
                    *(unsigned*)(Yb + (size_t)gr * 256 + 128 + c) = pack_bf16(acc[r].x, acc[r].y);
                    const float a0 = srow[wave * 8 + r][c];
                    const float a1 = srow[wave * 8 + r][c + 1];
                    *(unsigned*)(Yb + (size_t)gr * 256 + c) = pack_bf16(a0, a1);
                } else {
                    unsigned short* Yb = (unsigned short*)Yv;
                    *(unsigned*)(Yb + (size_t)gr * 128 + c) = pack_bf16(acc[r].x, acc[r].y);
                }
            }
        }
        __syncthreads();   // srow stable until here; next iter restages
    }
}

extern "C" void kernel_launch(void* const* d_in, const int* in_sizes, int n_in,
                              void* d_out, int out_size, void* d_ws, size_t ws_size,
                              hipStream_t stream) {
    const int*   q_rel  = (const int*)d_in[0];
    const float* hidden = (const float*)d_in[1];
    const int*   edges  = (const int*)d_in[2];
    const float* rela   = (const float*)d_in[3];
    const float* Ws     = (const float*)d_in[4];
    const float* Wr     = (const float*)d_in[5];
    const float* Wqr_w  = (const float*)d_in[6];
    const float* Wqr_b  = (const float*)d_in[7];
    const float* Wa     = (const float*)d_in[8];
    const float* Wh     = (const float*)d_in[9];

    const int B = in_sizes[0];
    const int N = in_sizes[1] / D;
    const int E = in_sizes[2] / 6;
    const int R = in_sizes[3] / D;

    unsigned short* combo   = (unsigned short*)d_ws;            // N*256 bf16
    unsigned short* hrcombo = combo + (size_t)N * 256;          // R*256 bf16
    unsigned short* qrb     = hrcombo + (size_t)R * 256;        // B*128 bf16
    int* count  = (int*)(qrb + (size_t)B * 128);                // N
    int* bsum   = count + N;                                    // 64
    int* start  = bsum + 64;                                    // N+1
    int* cursor = start + N + 1;                                // N
    unsigned* sorted = (unsigned*)(cursor + N);                 // E

    // CSR build
    hipMemsetAsync(count, 0, (size_t)N * sizeof(int), stream);
    hist_kernel<<<1024, 256, 0, stream>>>(edges, count, E);
    const int G = (N + 1023) / 1024;   // <=64 for N<=65536
    scan_partial<<<G, 1024, 0, stream>>>(count, bsum, N);
    scan_bsum<<<1, 64, 0, stream>>>(bsum, G);
    scan_final<<<G, 1024, 0, stream>>>(count, bsum, start, cursor, N);
    scatter_kernel<<<1024, 256, 0, stream>>>(edges, cursor, sorted, E);

    // projections (fused bf16 conversion)
    proj_t<1><<<782, 256, 0, stream>>>(hidden, Ws, nullptr, nullptr, combo, N, 0);
    proj_t<1><<<(R + 31) / 32, 256, 0, stream>>>(rela, Wr, nullptr, nullptr, hrcombo, R, 0);
    proj_t<2><<<(B + 31) / 32, 256, 0, stream>>>(rela, Wqr_w, Wqr_b, q_rel, qrb, B, 0);

    // gather aggregation -> d_out f32 (every row written exactly once)
    agg_v3<<<2048, 256, 0, stream>>>(sorted, start, combo, hrcombo, qrb, Wa,
                                     (float*)d_out, N);

    // out = relu(agg @ Wh), in-place f32
    proj_t<0><<<782, 256, 0, stream>>>((float*)d_out, Wh, nullptr, nullptr, d_out, N, 1);
}

// Round 4
// 176.116 us; speedup vs baseline: 4.1583x; 1.4476x over previous
//
#include <hip/hip_runtime.h>
#include <math.h>
#include <stdint.h>

#define D 128
typedef __attribute__((ext_vector_type(8))) short short8;
typedef __attribute__((ext_vector_type(4))) float f32x4;
typedef unsigned short ushort_t;

__device__ inline unsigned pack_bf16(float a, float b) {
    unsigned ua = __float_as_uint(a), ub = __float_as_uint(b);
    ua = (ua + 0x7fffu + ((ua >> 16) & 1u)) >> 16;   // RNE
    ub = (ub + 0x7fffu + ((ub >> 16) & 1u)) >> 16;
    return ua | (ub << 16);
}
__device__ inline ushort_t bf16_of(float f) {
    unsigned u = __float_as_uint(f);
    u = (u + 0x7fffu + ((u >> 16) & 1u)) >> 16;
    return (ushort_t)u;
}
__device__ inline float2 bf2_to_f2(unsigned u) {
    return make_float2(__uint_as_float(u << 16), __uint_as_float(u & 0xffff0000u));
}

// ---------------- histogram of obj ----------------
__global__ void hist_kernel(const int* __restrict__ edges, int* __restrict__ count, int E) {
    const int i = blockIdx.x * blockDim.x + threadIdx.x;
    const int stride = gridDim.x * blockDim.x;
    for (int e = i; e < E; e += stride)
        atomicAdd(&count[edges[e * 6 + 5]], 1);
}

// ---------------- 3-phase exclusive scan ----------------
__global__ void scan_partial(const int* __restrict__ count, int* __restrict__ bsum, int M) {
    __shared__ int wsum[16];
    const int t = threadIdx.x, lane = t & 63, w = t >> 6;
    const int i = blockIdx.x * 1024 + t;
    int v = (i < M) ? count[i] : 0;
    #pragma unroll
    for (int off = 32; off > 0; off >>= 1) v += __shfl_xor(v, off, 64);
    if (lane == 0) wsum[w] = v;
    __syncthreads();
    if (w == 0) {
        int s = (lane < 16) ? wsum[lane] : 0;
        #pragma unroll
        for (int off = 8; off > 0; off >>= 1) s += __shfl_xor(s, off, 16);
        if (lane == 0) bsum[blockIdx.x] = s;
    }
}

__global__ void scan_bsum(int* __restrict__ bsum, int G) {  // 1 block, 64 threads, G<=64
    const int t = threadIdx.x;
    const int v = (t < G) ? bsum[t] : 0;
    int x = v;
    #pragma unroll
    for (int off = 1; off < 64; off <<= 1) {
        int y = __shfl_up(x, off, 64);
        if (t >= off) x += y;
    }
    if (t < G) bsum[t] = x - v;
}

__global__ void scan_final(const int* __restrict__ count, const int* __restrict__ bsum,
                           int* __restrict__ start, int* __restrict__ cursor, int M) {
    __shared__ int wsum[16];
    const int t = threadIdx.x, lane = t & 63, w = t >> 6;
    const int i = blockIdx.x * 1024 + t;
    const int v = (i < M) ? count[i] : 0;
    int x = v;
    #pragma unroll
    for (int off = 1; off < 64; off <<= 1) {
        int y = __shfl_up(x, off, 64);
        if (lane >= off) x += y;
    }
    if (lane == 63) wsum[w] = x;
    __syncthreads();
    if (w == 0) {
        int s = (lane < 16) ? wsum[lane] : 0;
        int xs = s;
        #pragma unroll
        for (int off = 1; off < 16; off <<= 1) {
            int y = __shfl_up(xs, off, 64);
            if (lane >= off) xs += y;
        }
        if (lane < 16) wsum[lane] = xs - s;
    }
    __syncthreads();
    const int excl = x - v + wsum[w] + bsum[blockIdx.x];
    if (i < M) {
        start[i] = excl;
        cursor[i] = excl;
        if (i == M - 1) start[M] = excl + v;
    }
}

// ---------------- scatter edges into CSR order, packed uint32 ----------------
// sub:16 | rel:9 | r_idx:7
__global__ void scatter_kernel(const int* __restrict__ edges, int* __restrict__ cursor,
                               unsigned* __restrict__ sorted, int E) {
    const int i = blockIdx.x * blockDim.x + threadIdx.x;
    const int stride = gridDim.x * blockDim.x;
    for (int e = i; e < E; e += stride) {
        const int r_idx = edges[e * 6 + 0];
        const int rel   = edges[e * 6 + 2];
        const int sub   = edges[e * 6 + 4];
        const int obj   = edges[e * 6 + 5];
        const int pos = atomicAdd(&cursor[obj], 1);
        sorted[pos] = (unsigned)sub | ((unsigned)rel << 16) | ((unsigned)r_idx << 25);
    }
}

// ---------------- W -> W^T bf16 prep (4 matrices, 1 block each) ----------------
__global__ void prep_wt(const float* __restrict__ W0, const float* __restrict__ W1,
                        const float* __restrict__ W2, const float* __restrict__ W3,
                        ushort_t* __restrict__ Wt4) {
    __shared__ ushort_t sT[D * D];
    const float* src = blockIdx.x == 0 ? W0 : blockIdx.x == 1 ? W1 : blockIdx.x == 2 ? W2 : W3;
    ushort_t* dst = Wt4 + (size_t)blockIdx.x * (D * D);
    const int t = threadIdx.x;
    for (int i = t; i < D * D; i += 256) {
        const int k = i >> 7, col = i & 127;
        sT[col * D + k] = bf16_of(src[i]);
    }
    __syncthreads();
    const short8* s8 = (const short8*)sT;
    short8* d8 = (short8*)dst;
    for (int i = t; i < D * D / 8; i += 256) d8[i] = s8[i];
}

// ---------------- MFMA 128x128 projection: Y = relu?(X[rowidx?] @ W + bias) ----------------
// MODE 0: f32 out (in-place safe). MODE 1: bf16 combo out ([0:128]=bf16(X row), [128:256]=proj).
// MODE 2: bf16 proj out only.
template<int MODE>
__global__ __launch_bounds__(256, 3)
void gemm_t(const float* __restrict__ X, const ushort_t* __restrict__ Wt,  // bf16 [col][k]
            const float* __restrict__ bias, const int* __restrict__ rowidx,
            void* __restrict__ Yv, int M, int do_relu) {
    __shared__ ushort_t sW[D * D];   // 32 KB, XOR-swizzled
    __shared__ ushort_t sX[64 * D];  // 16 KB, XOR-swizzled
    const int t = threadIdx.x;
    {   // stage W^T once (coalesced global, swizzled LDS)
        const short8* src = (const short8*)Wt;
        for (int s = t; s < 2048; s += 256) {
            const int col = s >> 4;
            const int off = (s & 15) * 16;
            *(short8*)((char*)sW + col * 256 + (off ^ ((col & 7) << 4))) = src[s];
        }
    }
    const int wave = t >> 6, lane = t & 63;
    const int l15 = lane & 15, lg = lane >> 4;
    __syncthreads();
    for (int r0 = blockIdx.x * 64; r0 < M; r0 += gridDim.x * 64) {
        {   // stage 64 rows, f32 -> bf16: thread -> row t>>2, quarter t&3
            const int row = t >> 2, q = t & 3;
            const int gr = r0 + row;
            if (gr < M) {
                const int src = rowidx ? rowidx[gr] : gr;
                const float* xp = X + (size_t)src * D + q * 32;
                #pragma unroll
                for (int s = 0; s < 4; ++s) {
                    const float4 v0 = *(const float4*)(xp + s * 8);
                    const float4 v1 = *(const float4*)(xp + s * 8 + 4);
                    uint4 pk;
                    pk.x = pack_bf16(v0.x, v0.y); pk.y = pack_bf16(v0.z, v0.w);
                    pk.z = pack_bf16(v1.x, v1.y); pk.w = pack_bf16(v1.z, v1.w);
                    const int off = q * 64 + s * 16;
                    *(uint4*)((char*)sX + row * 256 + (off ^ ((row & 7) << 4))) = pk;
                    if (MODE == 1)   // combo[0:128] = bf16(input row)
                        *(uint4*)((ushort_t*)Yv + (size_t)gr * 256 + q * 32 + s * 8) = pk;
                }
            }
        }
        __syncthreads();
        f32x4 acc[8];
        #pragma unroll
        for (int ct = 0; ct < 8; ++ct) acc[ct] = (f32x4){0.f, 0.f, 0.f, 0.f};
        #pragma unroll
        for (int kc = 0; kc < 4; ++kc) {
            const int koff = kc * 64 + lg * 16;
            const int arow = wave * 16 + l15;
            const short8 afrag = *(const short8*)((char*)sX + arow * 256 + (koff ^ ((arow & 7) << 4)));
            #pragma unroll
            for (int ct = 0; ct < 8; ++ct) {
                const int col = ct * 16 + l15;
                const short8 bfrag = *(const short8*)((char*)sW + col * 256 + (koff ^ ((col & 7) << 4)));
                acc[ct] = __builtin_amdgcn_mfma_f32_16x16x32_bf16(afrag, bfrag, acc[ct], 0, 0, 0);
            }
        }
        __syncthreads();   // all LDS reads done before next-iter staging
        #pragma unroll
        for (int q2 = 0; q2 < 4; ++q2) {
            const int gr2 = r0 + wave * 16 + lg * 4 + q2;
            if (gr2 < M) {
                #pragma unroll
                for (int ct = 0; ct < 8; ++ct) {
                    const int col = ct * 16 + l15;
                    float v = acc[ct][q2];
                    if (bias) v += bias[col];
                    if (do_relu) v = fmaxf(v, 0.f);
                    if (MODE == 0)      ((float*)Yv)[(size_t)gr2 * D + col] = v;
                    else if (MODE == 1) ((ushort_t*)Yv)[(size_t)gr2 * 256 + 128 + col] = bf16_of(v);
                    else                ((ushort_t*)Yv)[(size_t)gr2 * 128 + col] = bf16_of(v);
                }
            }
        }
    }
}

// ---------------- per-node gather aggregation: 2 edges per wave, 4 cols/lane ----------------
__global__ void agg_v4(const unsigned* __restrict__ sorted, const int* __restrict__ start,
                       const ushort_t* __restrict__ combo,    // [N][256]: hidden | hs_proj
                       const ushort_t* __restrict__ hrcombo,  // [R][256]: rela | hr_proj
                       const ushort_t* __restrict__ qrb,      // [B][128]: qr_proj
                       const float* __restrict__ Wa,
                       float* __restrict__ out, int N) {
    const int gtid = blockIdx.x * blockDim.x + threadIdx.x;
    const int wave = gtid >> 6;
    const int lane = threadIdx.x & 63;
    const int nwaves = (gridDim.x * blockDim.x) >> 6;
    const int half = lane >> 5, sl = lane & 31;
    const int c = sl * 4;
    const float4 wa4 = *(const float4*)(Wa + c);
    for (int n = wave; n < N; n += nwaves) {
        const int e0 = start[n], e1 = start[n + 1];
        float4 acc = make_float4(0.f, 0.f, 0.f, 0.f);
        for (int e = e0 + half; e < e1; e += 2) {
            const unsigned rec = sorted[e];
            const int sub  = rec & 0xFFFF;
            const int rel  = (rec >> 16) & 0x1FF;
            const int ridx = rec >> 25;
            const uint2 uhid = *(const uint2*)(combo + (size_t)sub * 256 + c);
            const uint2 uhsp = *(const uint2*)(combo + (size_t)sub * 256 + 128 + c);
            const uint2 uhre = *(const uint2*)(hrcombo + (size_t)rel * 256 + c);
            const uint2 uhrp = *(const uint2*)(hrcombo + (size_t)rel * 256 + 128 + c);
            const uint2 uqrp = *(const uint2*)(qrb + (size_t)ridx * 128 + c);
            const float2 hsp0 = bf2_to_f2(uhsp.x), hsp1 = bf2_to_f2(uhsp.y);
            const float2 hrp0 = bf2_to_f2(uhrp.x), hrp1 = bf2_to_f2(uhrp.y);
            const float2 qrp0 = bf2_to_f2(uqrp.x), qrp1 = bf2_to_f2(uqrp.y);
            const float p0 = fmaxf(hsp0.x + hrp0.x + qrp0.x, 0.f);
            const float p1 = fmaxf(hsp0.y + hrp0.y + qrp0.y, 0.f);
            const float p2 = fmaxf(hsp1.x + hrp1.x + qrp1.x, 0.f);
            const float p3 = fmaxf(hsp1.y + hrp1.y + qrp1.y, 0.f);
            float part = fmaf(p0, wa4.x, fmaf(p1, wa4.y, fmaf(p2, wa4.z, p3 * wa4.w)));
            #pragma unroll
            for (int off = 16; off > 0; off >>= 1) part += __shfl_xor(part, off, 64);
            const float alpha = 1.f / (1.f + __expf(-part));
            const float2 hid0 = bf2_to_f2(uhid.x), hid1 = bf2_to_f2(uhid.y);
            const float2 hre0 = bf2_to_f2(uhre.x), hre1 = bf2_to_f2(uhre.y);
            acc.x = fmaf(hid0.x + hre0.x, alpha, acc.x);
            acc.y = fmaf(hid0.y + hre0.y, alpha, acc.y);
            acc.z = fmaf(hid1.x + hre1.x, alpha, acc.z);
            acc.w = fmaf(hid1.y + hre1.y, alpha, acc.w);
        }
        acc.x += __shfl_xor(acc.x, 32, 64);
        acc.y += __shfl_xor(acc.y, 32, 64);
        acc.z += __shfl_xor(acc.z, 32, 64);
        acc.w += __shfl_xor(acc.w, 32, 64);
        if (half == 0) *(float4*)(out + (size_t)n * D + c) = acc;
    }
}

extern "C" void kernel_launch(void* const* d_in, const int* in_sizes, int n_in,
                              void* d_out, int out_size, void* d_ws, size_t ws_size,
                              hipStream_t stream) {
    const int*   q_rel  = (const int*)d_in[0];
    const float* hidden = (const float*)d_in[1];
    const int*   edges  = (const int*)d_in[2];
    const float* rela   = (const float*)d_in[3];
    const float* Ws     = (const float*)d_in[4];
    const float* Wr     = (const float*)d_in[5];
    const float* Wqr_w  = (const float*)d_in[6];
    const float* Wqr_b  = (const float*)d_in[7];
    const float* Wa     = (const float*)d_in[8];
    const float* Wh     = (const float*)d_in[9];

    const int B = in_sizes[0];
    const int N = in_sizes[1] / D;
    const int E = in_sizes[2] / 6;
    const int R = in_sizes[3] / D;

    ushort_t* combo   = (ushort_t*)d_ws;                 // N*256 bf16
    ushort_t* hrcombo = combo + (size_t)N * 256;         // R*256 bf16
    ushort_t* qrb     = hrcombo + (size_t)R * 256;       // B*128 bf16
    ushort_t* Wt4     = qrb + (size_t)B * 128;           // 4*128*128 bf16
    int* count  = (int*)(Wt4 + 4 * D * D);               // N
    int* bsum   = count + N;                             // 64
    int* start  = bsum + 64;                             // N+1
    int* cursor = start + N + 1;                         // N
    unsigned* sorted = (unsigned*)(cursor + N);          // E

    // CSR build
    hipMemsetAsync(count, 0, (size_t)N * sizeof(int), stream);
    hist_kernel<<<1024, 256, 0, stream>>>(edges, count, E);
    const int G = (N + 1023) / 1024;
    scan_partial<<<G, 1024, 0, stream>>>(count, bsum, N);
    scan_bsum<<<1, 64, 0, stream>>>(bsum, G);
    scan_final<<<G, 1024, 0, stream>>>(count, bsum, start, cursor, N);
    scatter_kernel<<<1024, 256, 0, stream>>>(edges, cursor, sorted, E);

    // weight prep + MFMA projections (fused bf16 combo production)
    prep_wt<<<4, 256, 0, stream>>>(Ws, Wr, Wqr_w, Wh, Wt4);
    const int TB = (N + 63) / 64;
    gemm_t<1><<<TB, 256, 0, stream>>>(hidden, Wt4, nullptr, nullptr, combo, N, 0);
    gemm_t<1><<<(R + 63) / 64, 256, 0, stream>>>(rela, Wt4 + D * D, nullptr, nullptr, hrcombo, R, 0);
    gemm_t<2><<<(B + 63) / 64, 256, 0, stream>>>(rela, Wt4 + 2 * D * D, Wqr_b, q_rel, qrb, B, 0);

    // gather aggregation -> d_out f32
    agg_v4<<<2048, 256, 0, stream>>>(sorted, start, combo, hrcombo, qrb, Wa,
                                     (float*)d_out, N);

    // out = relu(agg @ Wh), in-place, MFMA
    gemm_t<0><<<TB, 256, 0, stream>>>((float*)d_out, Wt4 + 3 * D * D, nullptr, nullptr,
                                      d_out, N, 1);
}

// Round 6
// 162.586 us; speedup vs baseline: 4.5044x; 1.0832x over previous
//
#include <hip/hip_runtime.h>
#include <hip/hip_fp16.h>
#include <math.h>
#include <stdint.h>

#define D 128
typedef __attribute__((ext_vector_type(8))) _Float16 f16x8;
typedef __attribute__((ext_vector_type(4))) float f32x4;
typedef unsigned short ushort_t;

__device__ inline unsigned pack_f16(float a, float b) {
    __half2 h = __floats2half2_rn(a, b);
    return __builtin_bit_cast(unsigned, h);
}
__device__ inline ushort_t f16_of(float f) {
    __half h = __float2half_rn(f);
    return __builtin_bit_cast(ushort_t, h);
}
__device__ inline __half2 hmax2(__half2 a, __half2 b) {
    unsigned ua = __builtin_bit_cast(unsigned, a);
    unsigned ub = __builtin_bit_cast(unsigned, b);
    unsigned r;
    asm("v_pk_max_f16 %0, %1, %2" : "=v"(r) : "v"(ua), "v"(ub));
    return __builtin_bit_cast(__half2, r);
}

struct __align__(16) H8 { __half2 h[4]; };

// ---------------- histogram of obj ----------------
__global__ void hist_kernel(const int* __restrict__ edges, int* __restrict__ count, int E) {
    const int i = blockIdx.x * blockDim.x + threadIdx.x;
    const int stride = gridDim.x * blockDim.x;
    for (int e = i; e < E; e += stride)
        atomicAdd(&count[edges[e * 6 + 5]], 1);
}

// ---------------- 2-phase exclusive scan ----------------
__global__ void scan_partial(const int* __restrict__ count, int* __restrict__ bsum, int M) {
    __shared__ int wsum[16];
    const int t = threadIdx.x, lane = t & 63, w = t >> 6;
    const int i = blockIdx.x * 1024 + t;
    int v = (i < M) ? count[i] : 0;
    #pragma unroll
    for (int off = 32; off > 0; off >>= 1) v += __shfl_xor(v, off, 64);
    if (lane == 0) wsum[w] = v;
    __syncthreads();
    if (w == 0) {
        int s = (lane < 16) ? wsum[lane] : 0;
        #pragma unroll
        for (int off = 8; off > 0; off >>= 1) s += __shfl_xor(s, off, 16);
        if (lane == 0) bsum[blockIdx.x] = s;
    }
}

__global__ void scan_final(const int* __restrict__ count, const int* __restrict__ bsum,
                           int* __restrict__ start, int* __restrict__ cursor, int M, int G) {
    __shared__ int wsum[16];
    __shared__ int sboff;
    const int t = threadIdx.x, lane = t & 63, w = t >> 6;
    const int i = blockIdx.x * 1024 + t;
    const int v = (i < M) ? count[i] : 0;
    if (w == 0) {   // exclusive prefix of block sums, pick this block's offset
        int bv = (lane < G) ? bsum[lane] : 0;
        int bx = bv;
        #pragma unroll
        for (int off = 1; off < 64; off <<= 1) {
            int y = __shfl_up(bx, off, 64);
            if (lane >= off) bx += y;
        }
        if (lane == (blockIdx.x & 63)) sboff = bx - bv;
    }
    int x = v;
    #pragma unroll
    for (int off = 1; off < 64; off <<= 1) {
        int y = __shfl_up(x, off, 64);
        if (lane >= off) x += y;
    }
    if (lane == 63) wsum[w] = x;
    __syncthreads();
    if (w == 0) {
        int s = (lane < 16) ? wsum[lane] : 0;
        int xs = s;
        #pragma unroll
        for (int off = 1; off < 16; off <<= 1) {
            int y = __shfl_up(xs, off, 64);
            if (lane >= off) xs += y;
        }
        if (lane < 16) wsum[lane] = xs - s;
    }
    __syncthreads();
    const int excl = x - v + wsum[w] + sboff;
    if (i < M) {
        start[i] = excl;
        cursor[i] = excl;
        if (i == M - 1) start[M] = excl + v;
    }
}

// ---------------- scatter edges into CSR order, packed uint32 ----------------
// sub:16 | rel:9 | r_idx:7
__global__ void scatter_kernel(const int* __restrict__ edges, int* __restrict__ cursor,
                               unsigned* __restrict__ sorted, int E) {
    const int i = blockIdx.x * blockDim.x + threadIdx.x;
    const int stride = gridDim.x * blockDim.x;
    const uint2* e2 = (const uint2*)edges;
    for (int e = i; e < E; e += stride) {
        const unsigned r_idx = e2[e * 3 + 0].x;
        const unsigned rel   = e2[e * 3 + 1].x;
        const uint2 so       = e2[e * 3 + 2];     // .x=sub .y=obj
        const int pos = atomicAdd(&cursor[so.y], 1);
        sorted[pos] = so.x | (rel << 16) | (r_idx << 25);
    }
}

// ---------------- W -> W^T fp16 prep (4 matrices, 1 block each) ----------------
__global__ void prep_wt(const float* __restrict__ W0, const float* __restrict__ W1,
                        const float* __restrict__ W2, const float* __restrict__ W3,
                        ushort_t* __restrict__ Wt4) {
    __shared__ ushort_t sT[D * D];
    const float* src = blockIdx.x == 0 ? W0 : blockIdx.x == 1 ? W1 : blockIdx.x == 2 ? W2 : W3;
    ushort_t* dst = Wt4 + (size_t)blockIdx.x * (D * D);
    const int t = threadIdx.x;
    for (int i = t; i < D * D; i += 256) {
        const int k = i >> 7, col = i & 127;
        sT[col * D + k] = f16_of(src[i]);
    }
    __syncthreads();
    const uint4* s8 = (const uint4*)sT;
    uint4* d8 = (uint4*)dst;
    for (int i = t; i < D * D / 8; i += 256) d8[i] = s8[i];
}

// ---------------- MFMA (fp16) 128x128 projection: Y = relu?(X[rowidx?] @ W + bias) -------
// MODE 0: f32 out (in-place safe). MODE 1: fp16 combo out ([0:128]=f16(X row), [128:256]=proj).
// MODE 2: fp16 proj out only.
template<int MODE>
__global__ __launch_bounds__(256, 3)
void gemm_t(const float* __restrict__ X, const ushort_t* __restrict__ Wt,  // fp16 [col][k]
            const float* __restrict__ bias, const int* __restrict__ rowidx,
            void* __restrict__ Yv, int M, int do_relu) {
    __shared__ ushort_t sW[D * D];   // 32 KB, XOR-swizzled
    __shared__ ushort_t sX[64 * D];  // 16 KB, XOR-swizzled
    const int t = threadIdx.x;
    {   // stage W^T once (coalesced global, swizzled LDS)
        const uint4* src = (const uint4*)Wt;
        for (int s = t; s < 2048; s += 256) {
            const int col = s >> 4;
            const int off = (s & 15) * 16;
            *(uint4*)((char*)sW + col * 256 + (off ^ ((col & 7) << 4))) = src[s];
        }
    }
    const int wave = t >> 6, lane = t & 63;
    const int l15 = lane & 15, lg = lane >> 4;
    __syncthreads();
    for (int r0 = blockIdx.x * 64; r0 < M; r0 += gridDim.x * 64) {
        {   // stage 64 rows, f32 -> fp16: thread -> row t>>2, quarter t&3
            const int row = t >> 2, q = t & 3;
            const int gr = r0 + row;
            if (gr < M) {
                const int src = rowidx ? rowidx[gr] : gr;
                const float* xp = X + (size_t)src * D + q * 32;
                #pragma unroll
                for (int s = 0; s < 4; ++s) {
                    const float4 v0 = *(const float4*)(xp + s * 8);
                    const float4 v1 = *(const float4*)(xp + s * 8 + 4);
                    uint4 pk;
                    pk.x = pack_f16(v0.x, v0.y); pk.y = pack_f16(v0.z, v0.w);
                    pk.z = pack_f16(v1.x, v1.y); pk.w = pack_f16(v1.z, v1.w);
                    const int off = q * 64 + s * 16;
                    *(uint4*)((char*)sX + row * 256 + (off ^ ((row & 7) << 4))) = pk;
                    if (MODE == 1)   // combo[0:128] = f16(input row)
                        *(uint4*)((ushort_t*)Yv + (size_t)gr * 256 + q * 32 + s * 8) = pk;
                }
            }
        }
        __syncthreads();
        f32x4 acc[8];
        #pragma unroll
        for (int ct = 0; ct < 8; ++ct) acc[ct] = (f32x4){0.f, 0.f, 0.f, 0.f};
        #pragma unroll
        for (int kc = 0; kc < 4; ++kc) {
            const int koff = kc * 64 + lg * 16;
            const int arow = wave * 16 + l15;
            const f16x8 afrag = *(const f16x8*)((char*)sX + arow * 256 + (koff ^ ((arow & 7) << 4)));
            #pragma unroll
            for (int ct = 0; ct < 8; ++ct) {
                const int col = ct * 16 + l15;
                const f16x8 bfrag = *(const f16x8*)((char*)sW + col * 256 + (koff ^ ((col & 7) << 4)));
                acc[ct] = __builtin_amdgcn_mfma_f32_16x16x32_f16(afrag, bfrag, acc[ct], 0, 0, 0);
            }
        }
        __syncthreads();   // all LDS reads done before next-iter staging
        #pragma unroll
        for (int q2 = 0; q2 < 4; ++q2) {
            const int gr2 = r0 + wave * 16 + lg * 4 + q2;
            if (gr2 < M) {
                #pragma unroll
                for (int ct = 0; ct < 8; ++ct) {
                    const int col = ct * 16 + l15;
                    float v = acc[ct][q2];
                    if (bias) v += bias[col];
                    if (do_relu) v = fmaxf(v, 0.f);
                    if (MODE == 0)      ((float*)Yv)[(size_t)gr2 * D + col] = v;
                    else if (MODE == 1) ((ushort_t*)Yv)[(size_t)gr2 * 256 + 128 + col] = f16_of(v);
                    else                ((ushort_t*)Yv)[(size_t)gr2 * 128 + col] = f16_of(v);
                }
            }
        }
    }
}

// ---------------- per-node gather aggregation: 4 edges/wave, 8 cols/lane, fp16 packed ----
__global__ void agg_v5(const unsigned* __restrict__ sorted, const int* __restrict__ start,
                       const __half* __restrict__ combo,    // [N][256]: hidden | hs_proj
                       const __half* __restrict__ hrcombo,  // [R][256]: rela | hr_proj
                       const __half* __restrict__ qrb,      // [B][128]: qr_proj
                       const float* __restrict__ Wa,
                       float* __restrict__ out, int N) {
    const int gtid = blockIdx.x * blockDim.x + threadIdx.x;
    const int wave = gtid >> 6;
    const int lane = threadIdx.x & 63;
    const int nwaves = (gridDim.x * blockDim.x) >> 6;
    const int grp = lane >> 4;        // 0..3 : edge slot within wave
    const int sl  = lane & 15;        // 0..15
    const int c   = sl * 8;           // 8 cols per lane
    __half2 wah[4];
    {
        const float4 w0 = *(const float4*)(Wa + c);
        const float4 w1 = *(const float4*)(Wa + c + 4);
        wah[0] = __floats2half2_rn(w0.x, w0.y);
        wah[1] = __floats2half2_rn(w0.z, w0.w);
        wah[2] = __floats2half2_rn(w1.x, w1.y);
        wah[3] = __floats2half2_rn(w1.z, w1.w);
    }
    const __half2 zero2 = __floats2half2_rn(0.f, 0.f);
    for (int n = wave; n < N; n += nwaves) {
        const int e0 = start[n], e1 = start[n + 1];
        float acc[8] = {0.f, 0.f, 0.f, 0.f, 0.f, 0.f, 0.f, 0.f};
        for (int e = e0 + grp; e < e1; e += 4) {
            const unsigned rec = sorted[e];
            const int sub  = rec & 0xFFFF;
            const int rel  = (rec >> 16) & 0x1FF;
            const int ridx = rec >> 25;
            const H8 uhid = *(const H8*)(combo + (size_t)sub * 256 + c);
            const H8 uhsp = *(const H8*)(combo + (size_t)sub * 256 + 128 + c);
            const H8 uhre = *(const H8*)(hrcombo + (size_t)rel * 256 + c);
            const H8 uhrp = *(const H8*)(hrcombo + (size_t)rel * 256 + 128 + c);
            const H8 uqrp = *(const H8*)(qrb + (size_t)ridx * 128 + c);
            __half2 d2 = zero2;
            #pragma unroll
            for (int j = 0; j < 4; ++j) {
                const __half2 p = hmax2(__hadd2(__hadd2(uhsp.h[j], uhrp.h[j]), uqrp.h[j]), zero2);
                d2 = __hfma2(p, wah[j], d2);
            }
            float part = __low2float(d2) + __high2float(d2);
            #pragma unroll
            for (int off = 8; off > 0; off >>= 1) part += __shfl_xor(part, off, 64);
            const float alpha = 1.f / (1.f + __expf(-part));
            #pragma unroll
            for (int j = 0; j < 4; ++j) {
                const __half2 m = __hadd2(uhid.h[j], uhre.h[j]);
                acc[j * 2]     = fmaf(__low2float(m),  alpha, acc[j * 2]);
                acc[j * 2 + 1] = fmaf(__high2float(m), alpha, acc[j * 2 + 1]);
            }
        }
        #pragma unroll
        for (int j = 0; j < 8; ++j) {   // combine the 4 edge slots
            acc[j] += __shfl_xor(acc[j], 16, 64);
            acc[j] += __shfl_xor(acc[j], 32, 64);
        }
        if (grp == 0) {
            *(float4*)(out + (size_t)n * D + c)     = make_float4(acc[0], acc[1], acc[2], acc[3]);
            *(float4*)(out + (size_t)n * D + c + 4) = make_float4(acc[4], acc[5], acc[6], acc[7]);
        }
    }
}

extern "C" void kernel_launch(void* const* d_in, const int* in_sizes, int n_in,
                              void* d_out, int out_size, void* d_ws, size_t ws_size,
                              hipStream_t stream) {
    const int*   q_rel  = (const int*)d_in[0];
    const float* hidden = (const float*)d_in[1];
    const int*   edges  = (const int*)d_in[2];
    const float* rela   = (const float*)d_in[3];
    const float* Ws     = (const float*)d_in[4];
    const float* Wr     = (const float*)d_in[5];
    const float* Wqr_w  = (const float*)d_in[6];
    const float* Wqr_b  = (const float*)d_in[7];
    const float* Wa     = (const float*)d_in[8];
    const float* Wh     = (const float*)d_in[9];

    const int B = in_sizes[0];
    const int N = in_sizes[1] / D;
    const int E = in_sizes[2] / 6;
    const int R = in_sizes[3] / D;

    ushort_t* combo   = (ushort_t*)d_ws;                 // N*256 fp16
    ushort_t* hrcombo = combo + (size_t)N * 256;         // R*256 fp16
    ushort_t* qrb     = hrcombo + (size_t)R * 256;       // B*128 fp16
    ushort_t* Wt4     = qrb + (size_t)B * 128;           // 4*128*128 fp16
    int* count  = (int*)(Wt4 + 4 * D * D);               // N
    int* bsum   = count + N;                             // 64
    int* start  = bsum + 64;                             // N+1
    int* cursor = start + N + 1;                         // N
    unsigned* sorted = (unsigned*)(cursor + N);          // E

    // CSR build
    (void)hipMemsetAsync(count, 0, (size_t)N * sizeof(int), stream);
    hist_kernel<<<1024, 256, 0, stream>>>(edges, count, E);
    const int G = (N + 1023) / 1024;
    scan_partial<<<G, 1024, 0, stream>>>(count, bsum, N);
    scan_final<<<G, 1024, 0, stream>>>(count, bsum, start, cursor, N, G);
    scatter_kernel<<<1024, 256, 0, stream>>>(edges, cursor, sorted, E);

    // weight prep + MFMA projections (fused fp16 combo production)
    prep_wt<<<4, 256, 0, stream>>>(Ws, Wr, Wqr_w, Wh, Wt4);
    const int TB = (N + 63) / 64;
    gemm_t<1><<<TB, 256, 0, stream>>>(hidden, Wt4, nullptr, nullptr, combo, N, 0);
    gemm_t<1><<<(R + 63) / 64, 256, 0, stream>>>(rela, Wt4 + D * D, nullptr, nullptr, hrcombo, R, 0);
    gemm_t<2><<<(B + 63) / 64, 256, 0, stream>>>(rela, Wt4 + 2 * D * D, Wqr_b, q_rel, qrb, B, 0);

    // gather aggregation -> d_out f32
    agg_v5<<<2048, 256, 0, stream>>>(sorted, start, (const __half*)combo,
                                     (const __half*)hrcombo, (const __half*)qrb, Wa,
                                     (float*)d_out, N);

    // out = relu(agg @ Wh), in-place, MFMA fp16
    gemm_t<0><<<TB, 256, 0, stream>>>((float*)d_out, Wt4 + 3 * D * D, nullptr, nullptr,
                                      d_out, N, 1);
}